// Round 17
// baseline (284.503 us; speedup 1.0000x reference)
//
#include <hip/hip_runtime.h>
#include <hip/hip_bf16.h>

// B=8 H=8 N=64 T=256 E=512 D=64 DH=64, TAU=1 -> scale 1/8
// Pipeline (reordered, exact same math as reference):
//   Qh = head-split(q@Wq^T), Kh = head-split(k@Wk^T)
//   Aperm[b,i,p]   = bf16 softmax_j(Qh.Kh^T/8), K-slot-permuted for MFMA frags
//   v'[b,h,j,s,d]  = sum_dd Wcat[d, h*64+dd] * v[b,h,j,s,dd]      (Wcat moved first; commutes)
//   V'[b,h,j,t,d]  = sum_{s<=t} Wconv[h,j,t,s] * v'[b,h,j,s,d]    (bf16 MFMA, reg-resident Wconv)
//   out[b,i,t,d]   = sum_{hj} A[i,hj] * V'[hj,td]  (MFMA; Vp transposed in-register via identity MFMA)
// NOTE: all fp32->bf16 packing uses integer RNE (f2bf) — hand-written
// v_cvt_pk_bf16_f32 inline asm caused NaNs in round 8; do not reintroduce.
// NOTE (round 17): batch loop chunked at bc=2 — conv writes a 32MB Vp slice and
// final immediately re-reads it while L3-resident (256MB MALL), removing most of
// the 256MB Vp round trip from HBM. Wconv is re-fetched per chunk but L3-caches.

typedef unsigned short u16;
typedef unsigned int u32;
typedef __attribute__((ext_vector_type(8))) short short8;
typedef __attribute__((ext_vector_type(4))) float f32x4;

static __device__ __forceinline__ u16 f2bf(float f) {
    u32 x; __builtin_memcpy(&x, &f, 4);
    u32 r = (x + 0x7fffu + ((x >> 16) & 1u)) >> 16;  // RNE
    return (u16)r;
}
static __device__ __forceinline__ short8 pack8(float4 a, float4 b) {
    short8 r;
    r[0] = (short)f2bf(a.x); r[1] = (short)f2bf(a.y);
    r[2] = (short)f2bf(a.z); r[3] = (short)f2bf(a.w);
    r[4] = (short)f2bf(b.x); r[5] = (short)f2bf(b.y);
    r[6] = (short)f2bf(b.z); r[7] = (short)f2bf(b.w);
    return r;
}
// pack two transpose-MFMA outputs (exact bf16 in f32 high bits) into a frag
static __device__ __forceinline__ short8 mk_bfrag(f32x4 a, f32x4 b) {
    u32 w0 = (__float_as_uint(a[0]) >> 16) | (__float_as_uint(a[1]) & 0xffff0000u);
    u32 w1 = (__float_as_uint(a[2]) >> 16) | (__float_as_uint(a[3]) & 0xffff0000u);
    u32 w2 = (__float_as_uint(b[0]) >> 16) | (__float_as_uint(b[1]) & 0xffff0000u);
    u32 w3 = (__float_as_uint(b[2]) >> 16) | (__float_as_uint(b[3]) & 0xffff0000u);
    uint4 u = make_uint4(w0, w1, w2, w3);
    short8 r; __builtin_memcpy(&r, &u, 16); return r;
}
// round two f32x4 accumulators into a bf16 A-frag (RNE)
static __device__ __forceinline__ short8 mk_bfrag_rnd(f32x4 a, f32x4 b) {
    short8 r;
    r[0] = (short)f2bf(a[0]); r[1] = (short)f2bf(a[1]);
    r[2] = (short)f2bf(a[2]); r[3] = (short)f2bf(a[3]);
    r[4] = (short)f2bf(b[0]); r[5] = (short)f2bf(b[1]);
    r[6] = (short)f2bf(b[2]); r[7] = (short)f2bf(b[3]);
    return r;
}
// pack 4 exact-bf16 f32 values into 8 bytes
static __device__ __forceinline__ uint2 pk4(f32x4 d) {
    return make_uint2((__float_as_uint(d[0]) >> 16) | (__float_as_uint(d[1]) & 0xffff0000u),
                      (__float_as_uint(d[2]) >> 16) | (__float_as_uint(d[3]) & 0xffff0000u));
}

// ---------------- K1: Q/K projection, C = X(512x512) @ W^T, head-split store ----
__global__ __launch_bounds__(256) void proj_qk(
        const float* __restrict__ q, const float* __restrict__ k,
        const float* __restrict__ Wq, const float* __restrict__ Wk,
        float* __restrict__ Qh, float* __restrict__ Kh) {
    const int et = blockIdx.x, rt = blockIdx.y, z = blockIdx.z;
    const float* X = z ? k : q;
    const float* W = z ? Wk : Wq;
    float* Out = z ? Kh : Qh;
    __shared__ float Xs[32][65];
    __shared__ float Ws[32][65];
    const int tid = threadIdx.x;
    const int tx = tid & 15, ty = tid >> 4;
    const int r0 = rt * 64, e0 = et * 64;
    float acc[4][4] = {};
    for (int k0 = 0; k0 < 512; k0 += 32) {
        __syncthreads();
        #pragma unroll
        for (int rep = 0; rep < 8; ++rep) {
            int lin = rep * 256 + tid;
            int kk = lin & 31, m = lin >> 5;
            Xs[kk][m] = X[(size_t)(r0 + m) * 512 + k0 + kk];
            Ws[kk][m] = W[(size_t)(e0 + m) * 512 + k0 + kk];
        }
        __syncthreads();
        #pragma unroll 8
        for (int kk = 0; kk < 32; ++kk) {
            float a0 = Xs[kk][4 * ty + 0], a1 = Xs[kk][4 * ty + 1];
            float a2 = Xs[kk][4 * ty + 2], a3 = Xs[kk][4 * ty + 3];
            float b0 = Ws[kk][4 * tx + 0], b1 = Ws[kk][4 * tx + 1];
            float b2 = Ws[kk][4 * tx + 2], b3 = Ws[kk][4 * tx + 3];
            acc[0][0] += a0 * b0; acc[0][1] += a0 * b1; acc[0][2] += a0 * b2; acc[0][3] += a0 * b3;
            acc[1][0] += a1 * b0; acc[1][1] += a1 * b1; acc[1][2] += a1 * b2; acc[1][3] += a1 * b3;
            acc[2][0] += a2 * b0; acc[2][1] += a2 * b1; acc[2][2] += a2 * b2; acc[2][3] += a2 * b3;
            acc[3][0] += a3 * b0; acc[3][1] += a3 * b1; acc[3][2] += a3 * b2; acc[3][3] += a3 * b3;
        }
    }
    #pragma unroll
    for (int i = 0; i < 4; ++i) {
        #pragma unroll
        for (int j = 0; j < 4; ++j) {
            int r = r0 + 4 * ty + i;   // b*64 + n
            int e = e0 + 4 * tx + j;   // h*64 + dh
            int b = r >> 6, n = r & 63, h = e >> 6, dh = e & 63;
            Out[(((size_t)(b * 8 + h) * 64 + n) * 64) + dh] = acc[i][j];
        }
    }
}

// ---------------- K2: scores + softmax -> Aperm[b,i,h*64+perm(j)] bf16 -----------
__global__ __launch_bounds__(256) void attn_softmax(
        const float* __restrict__ Qh, const float* __restrict__ Kh,
        u16* __restrict__ Aperm) {
    const int bh = blockIdx.x;          // b*8+h
    const int b = bh >> 3, h = bh & 7;
    const int tid = threadIdx.x;
    __shared__ float Qt[64][64];
    __shared__ float KT[64][65];
    const size_t base = (size_t)bh * 4096;
    #pragma unroll
    for (int rep = 0; rep < 16; ++rep) {
        int lin = rep * 256 + tid;
        int r = lin >> 6, c = lin & 63;
        Qt[r][c] = Qh[base + lin];
        KT[c][r] = Kh[base + lin];
    }
    __syncthreads();
    const int w = tid >> 6, lane = tid & 63;
    const int w31 = lane & 31;
    const int slot = (w31 < 16) ? ((w31 >> 2) * 8 + (w31 & 3))
                                : (((w31 - 16) >> 2) * 8 + 4 + (w31 & 3));
    const int p = h * 64 + (lane & 32) + slot;
    for (int rr = 0; rr < 16; ++rr) {
        int i = w + 4 * rr;
        float s = 0.f;
        #pragma unroll
        for (int dd = 0; dd < 64; ++dd) s += Qt[i][dd] * KT[dd][lane];
        s *= 0.125f;                      // 1/(TAU*sqrt(DH))
        float m = s;
        #pragma unroll
        for (int off = 32; off; off >>= 1) m = fmaxf(m, __shfl_xor(m, off));
        float e = __expf(s - m);
        float sum = e;
        #pragma unroll
        for (int off = 32; off; off >>= 1) sum += __shfl_xor(sum, off);
        Aperm[((size_t)(b * 64 + i) << 9) + p] = f2bf(e / sum);
    }
}

// ---------------- K3: conv, 8 waves/block. Wave w owns tiles {w, 15-w}: 9 frags.
template<int TI, int OFF>
__device__ __forceinline__ void load_tile(short8* wc, const float* __restrict__ wcb,
                                          int lo, int hi) {
    const int t = TI * 16 + lo;
    #pragma unroll
    for (int kk = 0; kk <= TI / 2; ++kk) {
        const float* p = wcb + (size_t)t * 256 + kk * 32 + hi * 8;
        float4 x = ((const float4*)p)[0], y = ((const float4*)p)[1];
        float wf[8] = {x.x, x.y, x.z, x.w, y.x, y.y, y.z, y.w};
        if (kk == TI / 2) {                // diagonal tile: mask s > t
            int sb = kk * 32 + hi * 8;
            #pragma unroll
            for (int e = 0; e < 8; ++e)
                if (sb + e > t) wf[e] = 0.f;
        }
        short8 af;
        #pragma unroll
        for (int e = 0; e < 8; ++e) af[e] = (short)f2bf(wf[e]);
        wc[OFF + kk] = af;
    }
}

template<int W>
__device__ __forceinline__ void load_wconv_w(short8 wc[9], const float* __restrict__ wcb,
                                             int lo, int hi) {
    load_tile<W,      0        >(wc, wcb, lo, hi);
    load_tile<15 - W, W / 2 + 1>(wc, wcb, lo, hi);
}

// Phase B for wave w: tiles A=w (kk<=W/2), B=15-w (kk<=(15-W)/2). Single-tile
// coalesced transpose store: Xc=(a,a) + J1 (J1 zeroes the upper-half garbage).
template<int W>
__device__ __forceinline__ void phaseB_w(const short8 wc[9], const u16* __restrict__ vptB,
        u16* __restrict__ vout, int lo, int hi, short8 J1) {
    constexpr int KA = W / 2, KB = (15 - W) / 2, OB = KA + 1;
    f32x4 aA[4] = {}, aB[4] = {};
    #pragma unroll
    for (int kk = 0; kk <= KB; ++kk) {
        short8 bfr[4];
        #pragma unroll
        for (int di = 0; di < 4; ++di) {
            int d = di * 16 + lo;
            int sc = kk * 4 + hi;
            bfr[di] = *(const short8*)&vptB[d * 256 + ((sc ^ (d & 7)) << 3)];  // ds_read_b128
        }
        #pragma unroll
        for (int di = 0; di < 4; ++di) {
            aB[di] = __builtin_amdgcn_mfma_f32_16x16x32_bf16(wc[OB + kk], bfr[di], aB[di], 0, 0, 0);
            if (kk <= KA)
                aA[di] = __builtin_amdgcn_mfma_f32_16x16x32_bf16(wc[kk], bfr[di], aA[di], 0, 0, 0);
        }
    }
    const f32x4 z = {};
    #pragma unroll
    for (int di = 0; di < 4; ++di) {
        short8 XcA = mk_bfrag_rnd(aA[di], aA[di]);   // rows W*16+pi(hi,e<4), col di*16+lo
        short8 XcB = mk_bfrag_rnd(aB[di], aB[di]);
        f32x4 DA = __builtin_amdgcn_mfma_f32_16x16x32_bf16(XcA, J1, z, 0, 0, 0);
        f32x4 DB = __builtin_amdgcn_mfma_f32_16x16x32_bf16(XcB, J1, z, 0, 0, 0);
        // lane(lo,hi) reg r = V'[TB+lo][di*16+hi*4+r]
        *(uint2*)&vout[(size_t)(W * 16 + lo) * 64 + di * 16 + hi * 4] = pk4(DA);
        *(uint2*)&vout[(size_t)((15 - W) * 16 + lo) * 64 + di * 16 + hi * 4] = pk4(DB);
    }
}

__global__ __launch_bounds__(512, 4) void conv_mfma(
        const float* __restrict__ v, const float* __restrict__ Wconv,
        const float* __restrict__ Wcat, u16* __restrict__ Vp,
        int b0, int bs) {
    const int hj = blockIdx.x, h = hj >> 6, j = hj & 63;
    const int tid = threadIdx.x;
    const int w = tid >> 6, l = tid & 63;    // 8 waves
    const int lo = l & 15, hi = l >> 4;

    __shared__ u16 vptB[64 * 256];     // 32 KB single buffer: v'T[d][s], swizzled
    __shared__ u16 wcatL[64 * 64];     // 8 KB: Wcat_h bf16, 16B-chunk XOR-swizzled

    // transpose-compensation identity frag: J1[e] = delta(pi(hi,e) == lo)
    short8 J1;
    #pragma unroll
    for (int e = 0; e < 8; ++e) {
        int pie = (e < 4) ? (hi * 4 + e) : (16 + hi * 4 + (e - 4));
        J1[e] = (pie == lo) ? (short)0x3F80 : (short)0;
    }

    // register-resident bf16 Wconv frags (9 tiles = 36 VGPR), loaded/masked once
    short8 wc[9];
    const float* wcb = Wconv + (size_t)hj * 65536;
    if (w == 0)      load_wconv_w<0>(wc, wcb, lo, hi);
    else if (w == 1) load_wconv_w<1>(wc, wcb, lo, hi);
    else if (w == 2) load_wconv_w<2>(wc, wcb, lo, hi);
    else if (w == 3) load_wconv_w<3>(wc, wcb, lo, hi);
    else if (w == 4) load_wconv_w<4>(wc, wcb, lo, hi);
    else if (w == 5) load_wconv_w<5>(wc, wcb, lo, hi);
    else if (w == 6) load_wconv_w<6>(wc, wcb, lo, hi);
    else             load_wconv_w<7>(wc, wcb, lo, hi);

    // Wcat_h -> LDS (once): thread covers 8 contiguous dd of one row d
    {
        int lin = tid * 8;
        int d = lin >> 6, dd0 = lin & 63;
        const float* p = Wcat + (size_t)d * 512 + h * 64 + dd0;
        short8 wv = pack8(((const float4*)p)[0], ((const float4*)p)[1]);
        *(short8*)&wcatL[d * 64 + (((dd0 >> 3) ^ (d & 7)) << 3)] = wv;
    }
    asm volatile("s_waitcnt lgkmcnt(0)" ::: "memory");
    __builtin_amdgcn_s_barrier();

    for (int i = 0; i < bs; ++i) {
        const int b = b0 + i;
        // wcat B-frags from LDS (per batch; 8 ds_read_b128, L0-hot)
        short8 wcat[2][4];
        #pragma unroll
        for (int kk = 0; kk < 2; ++kk)
            #pragma unroll
            for (int di = 0; di < 4; ++di) {
                int d = di * 16 + lo;
                int c8 = kk * 4 + hi;
                wcat[kk][di] = *(const short8*)&wcatL[d * 64 + ((c8 ^ (d & 7)) << 3)];
            }
        // ---- Phase A: v'(256x64) = v @ Wcat_h^T; wave w owns rows [w*32,w*32+32)
        const size_t vb = ((size_t)(b * 8 + h) * 64 + j) * 16384;
        #pragma unroll
        for (int si = 0; si < 2; ++si) {
            const float* p = v + vb + (size_t)(w * 32 + si * 16 + lo) * 64;
            const float4* q0 = (const float4*)(p + hi * 8);
            const float4* q1 = (const float4*)(p + 32 + hi * 8);
            short8 af0 = pack8(q0[0], q0[1]);
            short8 af1 = pack8(q1[0], q1[1]);
            f32x4 a4[4] = {};
            #pragma unroll
            for (int di = 0; di < 4; ++di) {
                a4[di] = __builtin_amdgcn_mfma_f32_16x16x32_bf16(af0, wcat[0][di], a4[di], 0, 0, 0);
                a4[di] = __builtin_amdgcn_mfma_f32_16x16x32_bf16(af1, wcat[1][di], a4[di], 0, 0, 0);
            }
            int s0 = w * 32 + si * 16 + hi * 4;
            #pragma unroll
            for (int di = 0; di < 4; ++di) {
                int d = di * 16 + lo;
                u32 lo32 = (u32)f2bf(a4[di][0]) | ((u32)f2bf(a4[di][1]) << 16);
                u32 hi32 = (u32)f2bf(a4[di][2]) | ((u32)f2bf(a4[di][3]) << 16);
                *(uint2*)&vptB[d * 256 + (((s0 >> 3) ^ (d & 7)) << 3) + (s0 & 7)] =
                    make_uint2(lo32, hi32);
            }
        }
        asm volatile("s_waitcnt lgkmcnt(0)" ::: "memory");
        __builtin_amdgcn_s_barrier();           // v' visible to all waves
        // ---- Phase B: V' = tril(Wconv) @ v', coalesced transpose stores ----
        u16* vout = Vp + ((size_t)i * 512 + hj) * 16384;
        if (w == 0)      phaseB_w<0>(wc, vptB, vout, lo, hi, J1);
        else if (w == 1) phaseB_w<1>(wc, vptB, vout, lo, hi, J1);
        else if (w == 2) phaseB_w<2>(wc, vptB, vout, lo, hi, J1);
        else if (w == 3) phaseB_w<3>(wc, vptB, vout, lo, hi, J1);
        else if (w == 4) phaseB_w<4>(wc, vptB, vout, lo, hi, J1);
        else if (w == 5) phaseB_w<5>(wc, vptB, vout, lo, hi, J1);
        else if (w == 6) phaseB_w<6>(wc, vptB, vout, lo, hi, J1);
        else             phaseB_w<7>(wc, vptB, vout, lo, hi, J1);
        asm volatile("s_waitcnt lgkmcnt(0)" ::: "memory");
        __builtin_amdgcn_s_barrier();           // reads done before next A writes
    }
}

// ---------------- K4: out[b](64x16384) = A(64x512) @ Vp(512x16384), MFMA ---------
// 2-deep software pipeline (A/B register sets), fully unrolled.
__global__ __launch_bounds__(256) void final_mfma(
        const u16* __restrict__ Aperm, const u16* __restrict__ Vp,
        float* __restrict__ out, int bbase) {
    const int nblk = blockIdx.x;
    const int bl = blockIdx.y, b = bbase + bl;
    const int tid = threadIdx.x;
    const int w = tid >> 6, l = tid & 63;
    const int lo = l & 15, hi = l >> 4;
    const int nb = nblk * 128 + w * 32;

    short8 I1, I2;
    #pragma unroll
    for (int e = 0; e < 8; ++e) {
        I1[e] = (hi * 8 + e == lo) ? (short)0x3F80 : (short)0;
        I2[e] = (hi * 8 + e == lo + 16) ? (short)0x3F80 : (short)0;
    }

    const u16* ab = Aperm + ((size_t)b << 15);               // b*64*512
    const u16* vb = Vp + (size_t)bl * 512 * 16384;

    f32x4 acc[4][2] = {};
    const f32x4 z = {};

    #define LDAF(af, k0) { \
        _Pragma("unroll") \
        for (int mi = 0; mi < 4; ++mi) \
            af[mi] = *(const short8*)&ab[(size_t)(mi * 16 + lo) * 512 + (k0) + hi * 8]; }
    #define LDX(X1, X2, k0) { \
        X1 = *(const short8*)&vb[(size_t)((k0) + lo) * 16384 + nb + hi * 8]; \
        X2 = *(const short8*)&vb[(size_t)((k0) + 16 + lo) * 16384 + nb + hi * 8]; }
    #define COMPUTE(af, X1, X2) { \
        f32x4 t1a = __builtin_amdgcn_mfma_f32_16x16x32_bf16(X1, I1, z, 0, 0, 0); \
        f32x4 t1b = __builtin_amdgcn_mfma_f32_16x16x32_bf16(X1, I2, z, 0, 0, 0); \
        f32x4 t2a = __builtin_amdgcn_mfma_f32_16x16x32_bf16(X2, I1, z, 0, 0, 0); \
        f32x4 t2b = __builtin_amdgcn_mfma_f32_16x16x32_bf16(X2, I2, z, 0, 0, 0); \
        short8 B0 = mk_bfrag(t1a, t2a); \
        short8 B1 = mk_bfrag(t1b, t2b); \
        _Pragma("unroll") \
        for (int mi = 0; mi < 4; ++mi) { \
            acc[mi][0] = __builtin_amdgcn_mfma_f32_16x16x32_bf16(af[mi], B0, acc[mi][0], 0, 0, 0); \
            acc[mi][1] = __builtin_amdgcn_mfma_f32_16x16x32_bf16(af[mi], B1, acc[mi][1], 0, 0, 0); \
        } }

    short8 afA[4], afB[4], X1A, X2A, X1B, X2B;
    LDAF(afA, 0); LDX(X1A, X2A, 0);
    #pragma unroll
    for (int ks = 0; ks < 16; ks += 2) {
        const int k1 = (ks + 1) * 32;
        const int k2 = ((ks + 2) & 15) * 32;    // wraps to 0 on last iter (dead)
        LDAF(afB, k1); LDX(X1B, X2B, k1);
        COMPUTE(afA, X1A, X2A);
        LDAF(afA, k2); LDX(X1A, X2A, k2);
        COMPUTE(afB, X1B, X2B);
    }
    #undef LDAF
    #undef LDX
    #undef COMPUTE

    float* ob = out + ((size_t)b << 20);                     // b*64*16384
    #pragma unroll
    for (int mi = 0; mi < 4; ++mi) {
        #pragma unroll
        for (int nt = 0; nt < 2; ++nt) {
            int td = nb + nt * 16 + lo;
            #pragma unroll
            for (int r = 0; r < 4; ++r) {
                int i = mi * 16 + hi * 4 + r;
                ob[(size_t)i * 16384 + td] = acc[mi][nt][r];
            }
        }
    }
}

extern "C" void kernel_launch(void* const* d_in, const int* in_sizes, int n_in,
                              void* d_out, int out_size, void* d_ws, size_t ws_size,
                              hipStream_t stream) {
    const float* q     = (const float*)d_in[0];
    const float* k     = (const float*)d_in[1];
    const float* v     = (const float*)d_in[2];
    const float* Wq    = (const float*)d_in[3];
    const float* Wk    = (const float*)d_in[4];
    const float* Wconv = (const float*)d_in[5];
    const float* Wcat  = (const float*)d_in[6];
    float* out = (float*)d_out;

    // ws layout: Aperm bf16 (512KB) | Qh (1MB) | Kh (1MB) | V' bf16 (bc x 16MB)
    u16* Aperm = (u16*)d_ws;
    float* Qh = (float*)(Aperm + 262144);
    float* Kh = Qh + 262144;
    u16* Vp = (u16*)(Kh + 262144);
    const size_t fixed = 262144 * 2 + (size_t)2 * 262144 * 4;

    // bc=2: Vp slice (32MB) stays L3-resident between conv write and final read.
    int bc = 2;
    while (bc > 1 && fixed + (size_t)bc * 512 * 16384 * 2 > ws_size) bc >>= 1;

    proj_qk<<<dim3(8, 8, 2), 256, 0, stream>>>(q, k, Wq, Wk, Qh, Kh);
    attn_softmax<<<64, 256, 0, stream>>>(Qh, Kh, Aperm);
    for (int b0 = 0; b0 < 8; b0 += bc) {
        conv_mfma<<<dim3(512), 512, 0, stream>>>(v, Wconv, Wcat, Vp, b0, bc);
        final_mfma<<<dim3(128, bc), 256, 0, stream>>>(Aperm, Vp, out, b0);
    }
}

// Round 18
// 218.968 us; speedup vs baseline: 1.2993x; 1.2993x over previous
//
#include <hip/hip_runtime.h>
#include <hip/hip_bf16.h>

// B=8 H=8 N=64 T=256 E=512 D=64 DH=64, TAU=1 -> scale 1/8
// Pipeline (reordered, exact same math as reference):
//   Qh = head-split(q@Wq^T), Kh = head-split(k@Wk^T)
//   Aperm[b,i,p]   = bf16 softmax_j(Qh.Kh^T/8), K-slot-permuted for MFMA frags
//   v'[b,h,j,s,d]  = sum_dd Wcat[d, h*64+dd] * v[b,h,j,s,dd]      (Wcat moved first; commutes)
//   V'[b,h,j,t,d]  = sum_{s<=t} Wconv[h,j,t,s] * v'[b,h,j,s,d]    (bf16 MFMA, reg-resident Wconv)
//   out[b,i,t,d]   = sum_{hj} A[i,hj] * V'[hj,td]  (MFMA; Vp transposed in-register via identity MFMA)
// NOTE: all fp32->bf16 packing uses integer RNE (f2bf) — hand-written
// v_cvt_pk_bf16_f32 inline asm caused NaNs in round 8; do not reintroduce.
// NOTE (round 18): bc REVERTED to 8 — round 17's bc=2 chunking regressed
// 220->284us (4x conv launches re-fetch Wconv + 8 serialized dispatch tails
// swamp any L3-residency gain on the Vp round trip). Do not re-chunk.

typedef unsigned short u16;
typedef unsigned int u32;
typedef __attribute__((ext_vector_type(8))) short short8;
typedef __attribute__((ext_vector_type(4))) float f32x4;

static __device__ __forceinline__ u16 f2bf(float f) {
    u32 x; __builtin_memcpy(&x, &f, 4);
    u32 r = (x + 0x7fffu + ((x >> 16) & 1u)) >> 16;  // RNE
    return (u16)r;
}
static __device__ __forceinline__ short8 pack8(float4 a, float4 b) {
    short8 r;
    r[0] = (short)f2bf(a.x); r[1] = (short)f2bf(a.y);
    r[2] = (short)f2bf(a.z); r[3] = (short)f2bf(a.w);
    r[4] = (short)f2bf(b.x); r[5] = (short)f2bf(b.y);
    r[6] = (short)f2bf(b.z); r[7] = (short)f2bf(b.w);
    return r;
}
// pack two transpose-MFMA outputs (exact bf16 in f32 high bits) into a frag
static __device__ __forceinline__ short8 mk_bfrag(f32x4 a, f32x4 b) {
    u32 w0 = (__float_as_uint(a[0]) >> 16) | (__float_as_uint(a[1]) & 0xffff0000u);
    u32 w1 = (__float_as_uint(a[2]) >> 16) | (__float_as_uint(a[3]) & 0xffff0000u);
    u32 w2 = (__float_as_uint(b[0]) >> 16) | (__float_as_uint(b[1]) & 0xffff0000u);
    u32 w3 = (__float_as_uint(b[2]) >> 16) | (__float_as_uint(b[3]) & 0xffff0000u);
    uint4 u = make_uint4(w0, w1, w2, w3);
    short8 r; __builtin_memcpy(&r, &u, 16); return r;
}
// round two f32x4 accumulators into a bf16 A-frag (RNE)
static __device__ __forceinline__ short8 mk_bfrag_rnd(f32x4 a, f32x4 b) {
    short8 r;
    r[0] = (short)f2bf(a[0]); r[1] = (short)f2bf(a[1]);
    r[2] = (short)f2bf(a[2]); r[3] = (short)f2bf(a[3]);
    r[4] = (short)f2bf(b[0]); r[5] = (short)f2bf(b[1]);
    r[6] = (short)f2bf(b[2]); r[7] = (short)f2bf(b[3]);
    return r;
}
// pack 4 exact-bf16 f32 values into 8 bytes
static __device__ __forceinline__ uint2 pk4(f32x4 d) {
    return make_uint2((__float_as_uint(d[0]) >> 16) | (__float_as_uint(d[1]) & 0xffff0000u),
                      (__float_as_uint(d[2]) >> 16) | (__float_as_uint(d[3]) & 0xffff0000u));
}

// ---------------- K1: Q/K projection, C = X(512x512) @ W^T, head-split store ----
__global__ __launch_bounds__(256) void proj_qk(
        const float* __restrict__ q, const float* __restrict__ k,
        const float* __restrict__ Wq, const float* __restrict__ Wk,
        float* __restrict__ Qh, float* __restrict__ Kh) {
    const int et = blockIdx.x, rt = blockIdx.y, z = blockIdx.z;
    const float* X = z ? k : q;
    const float* W = z ? Wk : Wq;
    float* Out = z ? Kh : Qh;
    __shared__ float Xs[32][65];
    __shared__ float Ws[32][65];
    const int tid = threadIdx.x;
    const int tx = tid & 15, ty = tid >> 4;
    const int r0 = rt * 64, e0 = et * 64;
    float acc[4][4] = {};
    for (int k0 = 0; k0 < 512; k0 += 32) {
        __syncthreads();
        #pragma unroll
        for (int rep = 0; rep < 8; ++rep) {
            int lin = rep * 256 + tid;
            int kk = lin & 31, m = lin >> 5;
            Xs[kk][m] = X[(size_t)(r0 + m) * 512 + k0 + kk];
            Ws[kk][m] = W[(size_t)(e0 + m) * 512 + k0 + kk];
        }
        __syncthreads();
        #pragma unroll 8
        for (int kk = 0; kk < 32; ++kk) {
            float a0 = Xs[kk][4 * ty + 0], a1 = Xs[kk][4 * ty + 1];
            float a2 = Xs[kk][4 * ty + 2], a3 = Xs[kk][4 * ty + 3];
            float b0 = Ws[kk][4 * tx + 0], b1 = Ws[kk][4 * tx + 1];
            float b2 = Ws[kk][4 * tx + 2], b3 = Ws[kk][4 * tx + 3];
            acc[0][0] += a0 * b0; acc[0][1] += a0 * b1; acc[0][2] += a0 * b2; acc[0][3] += a0 * b3;
            acc[1][0] += a1 * b0; acc[1][1] += a1 * b1; acc[1][2] += a1 * b2; acc[1][3] += a1 * b3;
            acc[2][0] += a2 * b0; acc[2][1] += a2 * b1; acc[2][2] += a2 * b2; acc[2][3] += a2 * b3;
            acc[3][0] += a3 * b0; acc[3][1] += a3 * b1; acc[3][2] += a3 * b2; acc[3][3] += a3 * b3;
        }
    }
    #pragma unroll
    for (int i = 0; i < 4; ++i) {
        #pragma unroll
        for (int j = 0; j < 4; ++j) {
            int r = r0 + 4 * ty + i;   // b*64 + n
            int e = e0 + 4 * tx + j;   // h*64 + dh
            int b = r >> 6, n = r & 63, h = e >> 6, dh = e & 63;
            Out[(((size_t)(b * 8 + h) * 64 + n) * 64) + dh] = acc[i][j];
        }
    }
}

// ---------------- K2: scores + softmax -> Aperm[b,i,h*64+perm(j)] bf16 -----------
__global__ __launch_bounds__(256) void attn_softmax(
        const float* __restrict__ Qh, const float* __restrict__ Kh,
        u16* __restrict__ Aperm) {
    const int bh = blockIdx.x;          // b*8+h
    const int b = bh >> 3, h = bh & 7;
    const int tid = threadIdx.x;
    __shared__ float Qt[64][64];
    __shared__ float KT[64][65];
    const size_t base = (size_t)bh * 4096;
    #pragma unroll
    for (int rep = 0; rep < 16; ++rep) {
        int lin = rep * 256 + tid;
        int r = lin >> 6, c = lin & 63;
        Qt[r][c] = Qh[base + lin];
        KT[c][r] = Kh[base + lin];
    }
    __syncthreads();
    const int w = tid >> 6, lane = tid & 63;
    const int w31 = lane & 31;
    const int slot = (w31 < 16) ? ((w31 >> 2) * 8 + (w31 & 3))
                                : (((w31 - 16) >> 2) * 8 + 4 + (w31 & 3));
    const int p = h * 64 + (lane & 32) + slot;
    for (int rr = 0; rr < 16; ++rr) {
        int i = w + 4 * rr;
        float s = 0.f;
        #pragma unroll
        for (int dd = 0; dd < 64; ++dd) s += Qt[i][dd] * KT[dd][lane];
        s *= 0.125f;                      // 1/(TAU*sqrt(DH))
        float m = s;
        #pragma unroll
        for (int off = 32; off; off >>= 1) m = fmaxf(m, __shfl_xor(m, off));
        float e = __expf(s - m);
        float sum = e;
        #pragma unroll
        for (int off = 32; off; off >>= 1) sum += __shfl_xor(sum, off);
        Aperm[((size_t)(b * 64 + i) << 9) + p] = f2bf(e / sum);
    }
}

// ---------------- K3: conv, 8 waves/block. Wave w owns tiles {w, 15-w}: 9 frags.
template<int TI, int OFF>
__device__ __forceinline__ void load_tile(short8* wc, const float* __restrict__ wcb,
                                          int lo, int hi) {
    const int t = TI * 16 + lo;
    #pragma unroll
    for (int kk = 0; kk <= TI / 2; ++kk) {
        const float* p = wcb + (size_t)t * 256 + kk * 32 + hi * 8;
        float4 x = ((const float4*)p)[0], y = ((const float4*)p)[1];
        float wf[8] = {x.x, x.y, x.z, x.w, y.x, y.y, y.z, y.w};
        if (kk == TI / 2) {                // diagonal tile: mask s > t
            int sb = kk * 32 + hi * 8;
            #pragma unroll
            for (int e = 0; e < 8; ++e)
                if (sb + e > t) wf[e] = 0.f;
        }
        short8 af;
        #pragma unroll
        for (int e = 0; e < 8; ++e) af[e] = (short)f2bf(wf[e]);
        wc[OFF + kk] = af;
    }
}

template<int W>
__device__ __forceinline__ void load_wconv_w(short8 wc[9], const float* __restrict__ wcb,
                                             int lo, int hi) {
    load_tile<W,      0        >(wc, wcb, lo, hi);
    load_tile<15 - W, W / 2 + 1>(wc, wcb, lo, hi);
}

// Phase B for wave w: tiles A=w (kk<=W/2), B=15-w (kk<=(15-W)/2). Single-tile
// coalesced transpose store: Xc=(a,a) + J1 (J1 zeroes the upper-half garbage).
template<int W>
__device__ __forceinline__ void phaseB_w(const short8 wc[9], const u16* __restrict__ vptB,
        u16* __restrict__ vout, int lo, int hi, short8 J1) {
    constexpr int KA = W / 2, KB = (15 - W) / 2, OB = KA + 1;
    f32x4 aA[4] = {}, aB[4] = {};
    #pragma unroll
    for (int kk = 0; kk <= KB; ++kk) {
        short8 bfr[4];
        #pragma unroll
        for (int di = 0; di < 4; ++di) {
            int d = di * 16 + lo;
            int sc = kk * 4 + hi;
            bfr[di] = *(const short8*)&vptB[d * 256 + ((sc ^ (d & 7)) << 3)];  // ds_read_b128
        }
        #pragma unroll
        for (int di = 0; di < 4; ++di) {
            aB[di] = __builtin_amdgcn_mfma_f32_16x16x32_bf16(wc[OB + kk], bfr[di], aB[di], 0, 0, 0);
            if (kk <= KA)
                aA[di] = __builtin_amdgcn_mfma_f32_16x16x32_bf16(wc[kk], bfr[di], aA[di], 0, 0, 0);
        }
    }
    const f32x4 z = {};
    #pragma unroll
    for (int di = 0; di < 4; ++di) {
        short8 XcA = mk_bfrag_rnd(aA[di], aA[di]);   // rows W*16+pi(hi,e<4), col di*16+lo
        short8 XcB = mk_bfrag_rnd(aB[di], aB[di]);
        f32x4 DA = __builtin_amdgcn_mfma_f32_16x16x32_bf16(XcA, J1, z, 0, 0, 0);
        f32x4 DB = __builtin_amdgcn_mfma_f32_16x16x32_bf16(XcB, J1, z, 0, 0, 0);
        // lane(lo,hi) reg r = V'[TB+lo][di*16+hi*4+r]
        *(uint2*)&vout[(size_t)(W * 16 + lo) * 64 + di * 16 + hi * 4] = pk4(DA);
        *(uint2*)&vout[(size_t)((15 - W) * 16 + lo) * 64 + di * 16 + hi * 4] = pk4(DB);
    }
}

__global__ __launch_bounds__(512, 4) void conv_mfma(
        const float* __restrict__ v, const float* __restrict__ Wconv,
        const float* __restrict__ Wcat, u16* __restrict__ Vp,
        int b0, int bs) {
    const int hj = blockIdx.x, h = hj >> 6, j = hj & 63;
    const int tid = threadIdx.x;
    const int w = tid >> 6, l = tid & 63;    // 8 waves
    const int lo = l & 15, hi = l >> 4;

    __shared__ u16 vptB[64 * 256];     // 32 KB single buffer: v'T[d][s], swizzled
    __shared__ u16 wcatL[64 * 64];     // 8 KB: Wcat_h bf16, 16B-chunk XOR-swizzled

    // transpose-compensation identity frag: J1[e] = delta(pi(hi,e) == lo)
    short8 J1;
    #pragma unroll
    for (int e = 0; e < 8; ++e) {
        int pie = (e < 4) ? (hi * 4 + e) : (16 + hi * 4 + (e - 4));
        J1[e] = (pie == lo) ? (short)0x3F80 : (short)0;
    }

    // register-resident bf16 Wconv frags (9 tiles = 36 VGPR), loaded/masked once
    short8 wc[9];
    const float* wcb = Wconv + (size_t)hj * 65536;
    if (w == 0)      load_wconv_w<0>(wc, wcb, lo, hi);
    else if (w == 1) load_wconv_w<1>(wc, wcb, lo, hi);
    else if (w == 2) load_wconv_w<2>(wc, wcb, lo, hi);
    else if (w == 3) load_wconv_w<3>(wc, wcb, lo, hi);
    else if (w == 4) load_wconv_w<4>(wc, wcb, lo, hi);
    else if (w == 5) load_wconv_w<5>(wc, wcb, lo, hi);
    else if (w == 6) load_wconv_w<6>(wc, wcb, lo, hi);
    else             load_wconv_w<7>(wc, wcb, lo, hi);

    // Wcat_h -> LDS (once): thread covers 8 contiguous dd of one row d
    {
        int lin = tid * 8;
        int d = lin >> 6, dd0 = lin & 63;
        const float* p = Wcat + (size_t)d * 512 + h * 64 + dd0;
        short8 wv = pack8(((const float4*)p)[0], ((const float4*)p)[1]);
        *(short8*)&wcatL[d * 64 + (((dd0 >> 3) ^ (d & 7)) << 3)] = wv;
    }
    asm volatile("s_waitcnt lgkmcnt(0)" ::: "memory");
    __builtin_amdgcn_s_barrier();

    for (int i = 0; i < bs; ++i) {
        const int b = b0 + i;
        // wcat B-frags from LDS (per batch; 8 ds_read_b128, L0-hot)
        short8 wcat[2][4];
        #pragma unroll
        for (int kk = 0; kk < 2; ++kk)
            #pragma unroll
            for (int di = 0; di < 4; ++di) {
                int d = di * 16 + lo;
                int c8 = kk * 4 + hi;
                wcat[kk][di] = *(const short8*)&wcatL[d * 64 + ((c8 ^ (d & 7)) << 3)];
            }
        // ---- Phase A: v'(256x64) = v @ Wcat_h^T; wave w owns rows [w*32,w*32+32)
        const size_t vb = ((size_t)(b * 8 + h) * 64 + j) * 16384;
        #pragma unroll
        for (int si = 0; si < 2; ++si) {
            const float* p = v + vb + (size_t)(w * 32 + si * 16 + lo) * 64;
            const float4* q0 = (const float4*)(p + hi * 8);
            const float4* q1 = (const float4*)(p + 32 + hi * 8);
            short8 af0 = pack8(q0[0], q0[1]);
            short8 af1 = pack8(q1[0], q1[1]);
            f32x4 a4[4] = {};
            #pragma unroll
            for (int di = 0; di < 4; ++di) {
                a4[di] = __builtin_amdgcn_mfma_f32_16x16x32_bf16(af0, wcat[0][di], a4[di], 0, 0, 0);
                a4[di] = __builtin_amdgcn_mfma_f32_16x16x32_bf16(af1, wcat[1][di], a4[di], 0, 0, 0);
            }
            int s0 = w * 32 + si * 16 + hi * 4;
            #pragma unroll
            for (int di = 0; di < 4; ++di) {
                int d = di * 16 + lo;
                u32 lo32 = (u32)f2bf(a4[di][0]) | ((u32)f2bf(a4[di][1]) << 16);
                u32 hi32 = (u32)f2bf(a4[di][2]) | ((u32)f2bf(a4[di][3]) << 16);
                *(uint2*)&vptB[d * 256 + (((s0 >> 3) ^ (d & 7)) << 3) + (s0 & 7)] =
                    make_uint2(lo32, hi32);
            }
        }
        asm volatile("s_waitcnt lgkmcnt(0)" ::: "memory");
        __builtin_amdgcn_s_barrier();           // v' visible to all waves
        // ---- Phase B: V' = tril(Wconv) @ v', coalesced transpose stores ----
        u16* vout = Vp + ((size_t)i * 512 + hj) * 16384;
        if (w == 0)      phaseB_w<0>(wc, vptB, vout, lo, hi, J1);
        else if (w == 1) phaseB_w<1>(wc, vptB, vout, lo, hi, J1);
        else if (w == 2) phaseB_w<2>(wc, vptB, vout, lo, hi, J1);
        else if (w == 3) phaseB_w<3>(wc, vptB, vout, lo, hi, J1);
        else if (w == 4) phaseB_w<4>(wc, vptB, vout, lo, hi, J1);
        else if (w == 5) phaseB_w<5>(wc, vptB, vout, lo, hi, J1);
        else if (w == 6) phaseB_w<6>(wc, vptB, vout, lo, hi, J1);
        else             phaseB_w<7>(wc, vptB, vout, lo, hi, J1);
        asm volatile("s_waitcnt lgkmcnt(0)" ::: "memory");
        __builtin_amdgcn_s_barrier();           // reads done before next A writes
    }
}

// ---------------- K4: out[b](64x16384) = A(64x512) @ Vp(512x16384), MFMA ---------
// 2-deep software pipeline (A/B register sets), fully unrolled.
__global__ __launch_bounds__(256) void final_mfma(
        const u16* __restrict__ Aperm, const u16* __restrict__ Vp,
        float* __restrict__ out, int bbase) {
    const int nblk = blockIdx.x;
    const int bl = blockIdx.y, b = bbase + bl;
    const int tid = threadIdx.x;
    const int w = tid >> 6, l = tid & 63;
    const int lo = l & 15, hi = l >> 4;
    const int nb = nblk * 128 + w * 32;

    short8 I1, I2;
    #pragma unroll
    for (int e = 0; e < 8; ++e) {
        I1[e] = (hi * 8 + e == lo) ? (short)0x3F80 : (short)0;
        I2[e] = (hi * 8 + e == lo + 16) ? (short)0x3F80 : (short)0;
    }

    const u16* ab = Aperm + ((size_t)b << 15);               // b*64*512
    const u16* vb = Vp + (size_t)bl * 512 * 16384;

    f32x4 acc[4][2] = {};
    const f32x4 z = {};

    #define LDAF(af, k0) { \
        _Pragma("unroll") \
        for (int mi = 0; mi < 4; ++mi) \
            af[mi] = *(const short8*)&ab[(size_t)(mi * 16 + lo) * 512 + (k0) + hi * 8]; }
    #define LDX(X1, X2, k0) { \
        X1 = *(const short8*)&vb[(size_t)((k0) + lo) * 16384 + nb + hi * 8]; \
        X2 = *(const short8*)&vb[(size_t)((k0) + 16 + lo) * 16384 + nb + hi * 8]; }
    #define COMPUTE(af, X1, X2) { \
        f32x4 t1a = __builtin_amdgcn_mfma_f32_16x16x32_bf16(X1, I1, z, 0, 0, 0); \
        f32x4 t1b = __builtin_amdgcn_mfma_f32_16x16x32_bf16(X1, I2, z, 0, 0, 0); \
        f32x4 t2a = __builtin_amdgcn_mfma_f32_16x16x32_bf16(X2, I1, z, 0, 0, 0); \
        f32x4 t2b = __builtin_amdgcn_mfma_f32_16x16x32_bf16(X2, I2, z, 0, 0, 0); \
        short8 B0 = mk_bfrag(t1a, t2a); \
        short8 B1 = mk_bfrag(t1b, t2b); \
        _Pragma("unroll") \
        for (int mi = 0; mi < 4; ++mi) { \
            acc[mi][0] = __builtin_amdgcn_mfma_f32_16x16x32_bf16(af[mi], B0, acc[mi][0], 0, 0, 0); \
            acc[mi][1] = __builtin_amdgcn_mfma_f32_16x16x32_bf16(af[mi], B1, acc[mi][1], 0, 0, 0); \
        } }

    short8 afA[4], afB[4], X1A, X2A, X1B, X2B;
    LDAF(afA, 0); LDX(X1A, X2A, 0);
    #pragma unroll
    for (int ks = 0; ks < 16; ks += 2) {
        const int k1 = (ks + 1) * 32;
        const int k2 = ((ks + 2) & 15) * 32;    // wraps to 0 on last iter (dead)
        LDAF(afB, k1); LDX(X1B, X2B, k1);
        COMPUTE(afA, X1A, X2A);
        LDAF(afA, k2); LDX(X1A, X2A, k2);
        COMPUTE(afB, X1B, X2B);
    }
    #undef LDAF
    #undef LDX
    #undef COMPUTE

    float* ob = out + ((size_t)b << 20);                     // b*64*16384
    #pragma unroll
    for (int mi = 0; mi < 4; ++mi) {
        #pragma unroll
        for (int nt = 0; nt < 2; ++nt) {
            int td = nb + nt * 16 + lo;
            #pragma unroll
            for (int r = 0; r < 4; ++r) {
                int i = mi * 16 + hi * 4 + r;
                ob[(size_t)i * 16384 + td] = acc[mi][nt][r];
            }
        }
    }
}

extern "C" void kernel_launch(void* const* d_in, const int* in_sizes, int n_in,
                              void* d_out, int out_size, void* d_ws, size_t ws_size,
                              hipStream_t stream) {
    const float* q     = (const float*)d_in[0];
    const float* k     = (const float*)d_in[1];
    const float* v     = (const float*)d_in[2];
    const float* Wq    = (const float*)d_in[3];
    const float* Wk    = (const float*)d_in[4];
    const float* Wconv = (const float*)d_in[5];
    const float* Wcat  = (const float*)d_in[6];
    float* out = (float*)d_out;

    // ws layout: Aperm bf16 (512KB) | Qh (1MB) | Kh (1MB) | V' bf16 (up to 128MB)
    u16* Aperm = (u16*)d_ws;
    float* Qh = (float*)(Aperm + 262144);
    float* Kh = Qh + 262144;
    u16* Vp = (u16*)(Kh + 262144);
    const size_t fixed = 262144 * 2 + (size_t)2 * 262144 * 4;

    int bc = 8;  // batches per chunk; shrink if ws too small
    while (bc > 1 && fixed + (size_t)bc * 512 * 16384 * 2 > ws_size) bc >>= 1;

    proj_qk<<<dim3(8, 8, 2), 256, 0, stream>>>(q, k, Wq, Wk, Qh, Kh);
    attn_softmax<<<64, 256, 0, stream>>>(Qh, Kh, Aperm);
    for (int b0 = 0; b0 < 8; b0 += bc) {
        conv_mfma<<<dim3(512), 512, 0, stream>>>(v, Wconv, Wcat, Vp, b0, bc);
        final_mfma<<<dim3(128, bc), 256, 0, stream>>>(Aperm, Vp, out, b0);
    }
}